// Round 6
// baseline (201.229 us; speedup 1.0000x reference)
//
#include <hip/hip_runtime.h>

#define NN 50000
#define TT 12
#define QQ 3
#define HH 64
#define KK 32
#define TQ 36   // T*Q
#define NLEV 4

typedef float vf4 __attribute__((ext_vector_type(4)));  // native vec: ok for nontemporal builtins

// ---------------------------------------------------------------------------
// Projection: out[r][q] = sum_h gnn[r][h] * w[h][q] + b[q],  r in [0, N*T).
// Also writes a pristine copy (race-free source for same-level gathers).
// Wave handles 4 rows/iter: float4 load per lane (coalesced 1 KiB/wave),
// 16-lane shuffle-tree reduce. gnn is streamed non-temporally (153 MB,
// no reuse) to avoid evicting out/copy from L2 before the level kernels.
// ---------------------------------------------------------------------------
__global__ __launch_bounds__(256) void proj_kernel(
    const float* __restrict__ gnn, const float* __restrict__ w,
    const float* __restrict__ b, float* __restrict__ out,
    float* __restrict__ copy, int nrows)
{
    const int lane = threadIdx.x & 63;
    const int sub  = lane & 15;
    const int h0   = sub * 4;

    float wreg[4][3];
#pragma unroll
    for (int j = 0; j < 4; ++j)
#pragma unroll
        for (int q = 0; q < 3; ++q)
            wreg[j][q] = w[(h0 + j) * 3 + q];
    const float b0 = b[0], b1 = b[1], b2 = b[2];

    const int gwave  = (blockIdx.x * blockDim.x + threadIdx.x) >> 6;
    const int nwaves = (gridDim.x * blockDim.x) >> 6;
    const int nquads = nrows >> 2;

    for (int quad = gwave; quad < nquads; quad += nwaves) {
        const vf4 g = __builtin_nontemporal_load(
            reinterpret_cast<const vf4*>(gnn + (size_t)quad * 256 + lane * 4));
        float a0 = g.x * wreg[0][0] + g.y * wreg[1][0] + g.z * wreg[2][0] + g.w * wreg[3][0];
        float a1 = g.x * wreg[0][1] + g.y * wreg[1][1] + g.z * wreg[2][1] + g.w * wreg[3][1];
        float a2 = g.x * wreg[0][2] + g.y * wreg[1][2] + g.z * wreg[2][2] + g.w * wreg[3][2];
#pragma unroll
        for (int off = 8; off > 0; off >>= 1) {
            a0 += __shfl_down(a0, off);
            a1 += __shfl_down(a1, off);
            a2 += __shfl_down(a2, off);
        }
        if (sub == 0) {
            const int row = quad * 4 + (lane >> 4);
            out[row * 3 + 0] = a0 + b0;
            out[row * 3 + 1] = a1 + b1;
            out[row * 3 + 2] = a2 + b2;
            copy[row * 3 + 0] = a0 + b0;
            copy[row * 3 + 1] = a1 + b1;
            copy[row * 3 + 2] = a2 + b2;
        }
    }
}

// ---------------------------------------------------------------------------
// Prep: flag-encode keybom so agg needs no lvl[key] gather in its inner loop.
//   fkb = -1            if key < 0 (pad)
//   fkb = key | 1<<16   if lvl[key] == lvl[node]  (gather from pristine copy)
//   fkb = key           otherwise                 (gather from live out)
// key < 50000 < 2^16. Independent of proj output — pure index preprocessing.
// ---------------------------------------------------------------------------
__global__ __launch_bounds__(256) void prep_kernel(
    const int* __restrict__ keybom, const int* __restrict__ lvl,
    int* __restrict__ fkb)
{
    const int idx = blockIdx.x * blockDim.x + threadIdx.x;
    if (idx >= NN * KK) return;
    const int node = idx >> 5;           // KK = 32
    const int key  = keybom[idx];
    int enc = -1;
    if (key >= 0)
        enc = key | ((lvl[key] == lvl[node]) ? 0x10000 : 0);
    fkb[idx] = enc;
}

// ---------------------------------------------------------------------------
// One level, direct write, no lists/counts/atomics:
// thread = (node, tq) over all N; early-exit unless lvl[node]==level.
//   out[node][tq] = (sum_k src[key][tq] * sc[key][t]) / sc[node][t]
// src = copy for same-level keys (their pre-level value == projection value),
// else live out. Writers all have lvl==level; out-readers only touch keys
// with lvl!=level -> no read/write overlap within the dispatch.
// ---------------------------------------------------------------------------
__global__ __launch_bounds__(256) void agg_kernel(
    const float* __restrict__ copy, const float* __restrict__ scaler,
    const int* __restrict__ fkb, const int* __restrict__ lvl,
    float* out, int level)
{
    const int idx  = blockIdx.x * blockDim.x + threadIdx.x;
    const int node = idx / TQ;
    const int tq   = idx - node * TQ;
    if (node >= NN) return;
    if (lvl[node] != level) return;
    const int t = tq / QQ;

    const int* kb = fkb + (size_t)node * KK;
    float acc = 0.0f;
#pragma unroll 8
    for (int k = 0; k < KK; ++k) {
        const int enc = kb[k];
        if (enc < 0) continue;
        const int key = enc & 0xFFFF;
        const float* src = (enc & 0x10000) ? copy : out;
        acc += src[(size_t)key * TQ + tq] * scaler[key * TT + t];
    }
    out[(size_t)node * TQ + tq] = acc / scaler[node * TT + t];
}

extern "C" void kernel_launch(void* const* d_in, const int* in_sizes, int n_in,
                              void* d_out, int out_size, void* d_ws, size_t ws_size,
                              hipStream_t stream)
{
    const float* gnn    = (const float*)d_in[0];
    const float* w      = (const float*)d_in[1];
    const float* b      = (const float*)d_in[2];
    const float* scaler = (const float*)d_in[3];
    const int*   keybom = (const int*)d_in[4];
    const int*   lvl    = (const int*)d_in[5];
    float* out = (float*)d_out;

    char* ws = (char*)d_ws;
    int*   fkb  = (int*)ws;                               // NN*KK ints (6.4 MB)
    float* copy = (float*)(ws + (size_t)NN * KK * 4);     // NN*TQ floats (7.2 MB)

    // No memset, no atomics: R4's profile showed the 16-byte hipMemsetAsync
    // cost ~87 us/replay as a fillBufferAligned dispatch.

    prep_kernel<<<(NN * KK + 255) / 256, 256, 0, stream>>>(keybom, lvl, fkb);
    proj_kernel<<<2048, 256, 0, stream>>>(gnn, w, b, out, copy, NN * TT);

    const int blocks = (NN * TQ + 255) / 256;
    for (int level = 1; level < NLEV; ++level) {
        agg_kernel<<<blocks, 256, 0, stream>>>(copy, scaler, fkb, lvl, out, level);
    }
}

// Round 7
// 185.256 us; speedup vs baseline: 1.0862x; 1.0862x over previous
//
#include <hip/hip_runtime.h>

#define NN 50000
#define TT 12
#define QQ 3
#define HH 64
#define KK 32
#define TQ 36   // T*Q
#define NLEV 4

// ---------------------------------------------------------------------------
// Projection: bufA[r][q] = sum_h gnn[r][h] * w[h][q] + b[q],  r in [0, N*T).
// Wave handles 4 rows/iter: float4 load per lane (coalesced 1 KiB/wave),
// 16-lane shuffle-tree reduce.
// ---------------------------------------------------------------------------
__global__ __launch_bounds__(256) void proj_kernel(
    const float* __restrict__ gnn, const float* __restrict__ w,
    const float* __restrict__ b, float* __restrict__ out, int nrows)
{
    const int lane = threadIdx.x & 63;
    const int sub  = lane & 15;
    const int h0   = sub * 4;

    float wreg[4][3];
#pragma unroll
    for (int j = 0; j < 4; ++j)
#pragma unroll
        for (int q = 0; q < 3; ++q)
            wreg[j][q] = w[(h0 + j) * 3 + q];
    const float b0 = b[0], b1 = b[1], b2 = b[2];

    const int gwave  = (blockIdx.x * blockDim.x + threadIdx.x) >> 6;
    const int nwaves = (gridDim.x * blockDim.x) >> 6;
    const int nquads = nrows >> 2;

    for (int quad = gwave; quad < nquads; quad += nwaves) {
        const float4 g = *reinterpret_cast<const float4*>(gnn + (size_t)quad * 256 + lane * 4);
        float a0 = g.x * wreg[0][0] + g.y * wreg[1][0] + g.z * wreg[2][0] + g.w * wreg[3][0];
        float a1 = g.x * wreg[0][1] + g.y * wreg[1][1] + g.z * wreg[2][1] + g.w * wreg[3][1];
        float a2 = g.x * wreg[0][2] + g.y * wreg[1][2] + g.z * wreg[2][2] + g.w * wreg[3][2];
#pragma unroll
        for (int off = 8; off > 0; off >>= 1) {
            a0 += __shfl_down(a0, off);
            a1 += __shfl_down(a1, off);
            a2 += __shfl_down(a2, off);
        }
        if (sub == 0) {
            const int row = quad * 4 + (lane >> 4);
            out[row * 3 + 0] = a0 + b0;
            out[row * 3 + 1] = a1 + b1;
            out[row * 3 + 2] = a2 + b2;
        }
    }
}

// ---------------------------------------------------------------------------
// One level, ping-pong: nxt = level-L update of cur.
//   lvl[node]!=L : nxt[node][tq] = cur[node][tq]            (pass-through)
//   lvl[node]==L : nxt[node][tq] = (sum_k cur[key][tq]*sc[key][t]) / sc[node][t]
// Reads only the full pre-level state `cur` — exactly the reference semantics,
// so no race-avoidance copies/flags are needed at all. Single 7.2 MB gather
// source (vs 21 MB in R6) -> much better L2 behavior.
// ---------------------------------------------------------------------------
__global__ __launch_bounds__(256) void level_kernel(
    const float* __restrict__ cur, const float* __restrict__ scaler,
    const int* __restrict__ keybom, const int* __restrict__ lvl,
    float* __restrict__ nxt, int level)
{
    const int idx  = blockIdx.x * blockDim.x + threadIdx.x;
    if (idx >= NN * TQ) return;
    const int node = idx / TQ;
    const int tq   = idx - node * TQ;

    if (lvl[node] != level) {           // pass-through (coalesced stream)
        nxt[idx] = cur[idx];
        return;
    }

    const int t = tq / QQ;
    const int* kb = keybom + (size_t)node * KK;
    float acc = 0.0f;
#pragma unroll 8
    for (int k = 0; k < KK; ++k) {
        const int key = kb[k];
        if (key >= 0)
            acc += cur[(size_t)key * TQ + tq] * scaler[key * TT + t];
    }
    nxt[idx] = acc / scaler[node * TT + t];
}

extern "C" void kernel_launch(void* const* d_in, const int* in_sizes, int n_in,
                              void* d_out, int out_size, void* d_ws, size_t ws_size,
                              hipStream_t stream)
{
    const float* gnn    = (const float*)d_in[0];
    const float* w      = (const float*)d_in[1];
    const float* b      = (const float*)d_in[2];
    const float* scaler = (const float*)d_in[3];
    const int*   keybom = (const int*)d_in[4];
    const int*   lvl    = (const int*)d_in[5];
    float* out = (float*)d_out;

    char* ws = (char*)d_ws;
    float* bufA = (float*)ws;                                // NN*TQ floats (7.2 MB)
    float* bufB = (float*)(ws + (size_t)NN * TQ * 4);        // NN*TQ floats (7.2 MB)

    // proj -> A;  L1: A->B;  L2: B->A;  L3: A->d_out.
    // No memset (87us fill!), no atomics, no prep — 4 dispatches total.
    proj_kernel<<<2048, 256, 0, stream>>>(gnn, w, b, bufA, NN * TT);

    const int blocks = (NN * TQ + 255) / 256;
    level_kernel<<<blocks, 256, 0, stream>>>(bufA, scaler, keybom, lvl, bufB, 1);
    level_kernel<<<blocks, 256, 0, stream>>>(bufB, scaler, keybom, lvl, bufA, 2);
    level_kernel<<<blocks, 256, 0, stream>>>(bufA, scaler, keybom, lvl, out,  3);
}

// Round 8
// 168.836 us; speedup vs baseline: 1.1919x; 1.0973x over previous
//
#include <hip/hip_runtime.h>

#define NN 50000
#define TT 12
#define QQ 3
#define HH 64
#define KK 32
#define TQ 36   // T*Q
#define NLEV 4

// ---------------------------------------------------------------------------
// Projection in XW-space: bufA[node][t][q] = (proj(gnn)[node,t,q]) * sc[node,t].
// Key identity: the level update new_out = (sum_k out[key]*sc[key]) / sc[node]
// becomes XW_new[node] = sum_k XW[key] — the scaler cancels. So we carry
// XW = out*sc as the only live state and divide once at the end.
// Wave handles 4 rows/iter: float4 load per lane, 16-lane shuffle reduce.
// ---------------------------------------------------------------------------
__global__ __launch_bounds__(256) void proj_xw_kernel(
    const float* __restrict__ gnn, const float* __restrict__ w,
    const float* __restrict__ b, const float* __restrict__ scaler,
    float* __restrict__ xw, int nrows)
{
    const int lane = threadIdx.x & 63;
    const int sub  = lane & 15;
    const int h0   = sub * 4;

    float wreg[4][3];
#pragma unroll
    for (int j = 0; j < 4; ++j)
#pragma unroll
        for (int q = 0; q < 3; ++q)
            wreg[j][q] = w[(h0 + j) * 3 + q];
    const float b0 = b[0], b1 = b[1], b2 = b[2];

    const int gwave  = (blockIdx.x * blockDim.x + threadIdx.x) >> 6;
    const int nwaves = (gridDim.x * blockDim.x) >> 6;
    const int nquads = nrows >> 2;

    for (int quad = gwave; quad < nquads; quad += nwaves) {
        const float4 g = *reinterpret_cast<const float4*>(gnn + (size_t)quad * 256 + lane * 4);
        float a0 = g.x * wreg[0][0] + g.y * wreg[1][0] + g.z * wreg[2][0] + g.w * wreg[3][0];
        float a1 = g.x * wreg[0][1] + g.y * wreg[1][1] + g.z * wreg[2][1] + g.w * wreg[3][1];
        float a2 = g.x * wreg[0][2] + g.y * wreg[1][2] + g.z * wreg[2][2] + g.w * wreg[3][2];
#pragma unroll
        for (int off = 8; off > 0; off >>= 1) {
            a0 += __shfl_down(a0, off);
            a1 += __shfl_down(a1, off);
            a2 += __shfl_down(a2, off);
        }
        if (sub == 0) {
            const int row = quad * 4 + (lane >> 4);   // row = node*T + t
            const float s = scaler[row];              // scaler is [N][T] flat
            xw[row * 3 + 0] = (a0 + b0) * s;
            xw[row * 3 + 1] = (a1 + b1) * s;
            xw[row * 3 + 2] = (a2 + b2) * s;
        }
    }
}

// ---------------------------------------------------------------------------
// One level in XW-space, ping-pong: pure gather-sum, no scaler.
//   lvl[node]!=L : nxt[idx] = cur[idx]
//   lvl[node]==L : nxt[idx] = sum_k cur[key*36 + tq]
// The 36 threads of a node fetch each gathered 144-B key row exactly once,
// fully coalesced.
// ---------------------------------------------------------------------------
__global__ __launch_bounds__(256) void level_kernel(
    const float* __restrict__ cur, const int* __restrict__ keybom,
    const int* __restrict__ lvl, float* __restrict__ nxt, int level)
{
    const int idx  = blockIdx.x * blockDim.x + threadIdx.x;
    if (idx >= NN * TQ) return;
    const int node = idx / TQ;
    const int tq   = idx - node * TQ;

    if (lvl[node] != level) {
        nxt[idx] = cur[idx];
        return;
    }

    const int* kb = keybom + (size_t)node * KK;
    float acc = 0.0f;
#pragma unroll 8
    for (int k = 0; k < KK; ++k) {
        const int key = kb[k];
        if (key >= 0)
            acc += cur[(size_t)key * TQ + tq];
    }
    nxt[idx] = acc;
}

// ---------------------------------------------------------------------------
// Final level fused with the XW -> out conversion: for every node,
//   out[idx] = (lvl[node]==3 ? sum_k cur[key*36+tq] : cur[idx]) / sc[node,t]
// (one formula covers updated and pass-through nodes alike).
// ---------------------------------------------------------------------------
__global__ __launch_bounds__(256) void level_final_kernel(
    const float* __restrict__ cur, const float* __restrict__ scaler,
    const int* __restrict__ keybom, const int* __restrict__ lvl,
    float* __restrict__ out, int level)
{
    const int idx  = blockIdx.x * blockDim.x + threadIdx.x;
    if (idx >= NN * TQ) return;
    const int node = idx / TQ;

    float v;
    if (lvl[node] != level) {
        v = cur[idx];
    } else {
        const int tq = idx - node * TQ;
        const int* kb = keybom + (size_t)node * KK;
        float acc = 0.0f;
#pragma unroll 8
        for (int k = 0; k < KK; ++k) {
            const int key = kb[k];
            if (key >= 0)
                acc += cur[(size_t)key * TQ + tq];
        }
        v = acc;
    }
    out[idx] = v / scaler[idx / 3];      // idx/3 == node*T + t
}

extern "C" void kernel_launch(void* const* d_in, const int* in_sizes, int n_in,
                              void* d_out, int out_size, void* d_ws, size_t ws_size,
                              hipStream_t stream)
{
    const float* gnn    = (const float*)d_in[0];
    const float* w      = (const float*)d_in[1];
    const float* b      = (const float*)d_in[2];
    const float* scaler = (const float*)d_in[3];
    const int*   keybom = (const int*)d_in[4];
    const int*   lvl    = (const int*)d_in[5];
    float* out = (float*)d_out;

    char* ws = (char*)d_ws;
    float* bufA = (float*)ws;                                // NN*TQ floats (7.2 MB)
    float* bufB = (float*)(ws + (size_t)NN * TQ * 4);        // NN*TQ floats (7.2 MB)

    // 4 dispatches, no memset, no atomics, no scaler gathers in the levels.
    proj_xw_kernel<<<2048, 256, 0, stream>>>(gnn, w, b, scaler, bufA, NN * TT);

    const int blocks = (NN * TQ + 255) / 256;
    level_kernel<<<blocks, 256, 0, stream>>>(bufA, keybom, lvl, bufB, 1);
    level_kernel<<<blocks, 256, 0, stream>>>(bufB, keybom, lvl, bufA, 2);
    level_final_kernel<<<blocks, 256, 0, stream>>>(bufA, scaler, keybom, lvl, out, 3);
}

// Round 9
// 79.224 us; speedup vs baseline: 2.5400x; 2.1311x over previous
//
#include <hip/hip_runtime.h>

#define NN 50000
#define TT 12
#define QQ 3
#define HH 64
#define KK 32
#define TQ 36   // T*Q
#define NLEV 4

// ---------------------------------------------------------------------------
// Projection in XW-space: bufA[node][t][q] = proj(gnn)[node,t,q] * sc[node,t].
// Level update in XW-space is a pure gather-sum (scaler cancels): carried from R8.
// ---------------------------------------------------------------------------
__global__ __launch_bounds__(256) void proj_xw_kernel(
    const float* __restrict__ gnn, const float* __restrict__ w,
    const float* __restrict__ b, const float* __restrict__ scaler,
    float* __restrict__ xw, int nrows)
{
    const int lane = threadIdx.x & 63;
    const int sub  = lane & 15;
    const int h0   = sub * 4;

    float wreg[4][3];
#pragma unroll
    for (int j = 0; j < 4; ++j)
#pragma unroll
        for (int q = 0; q < 3; ++q)
            wreg[j][q] = w[(h0 + j) * 3 + q];
    const float b0 = b[0], b1 = b[1], b2 = b[2];

    const int gwave  = (blockIdx.x * blockDim.x + threadIdx.x) >> 6;
    const int nwaves = (gridDim.x * blockDim.x) >> 6;
    const int nquads = nrows >> 2;

    for (int quad = gwave; quad < nquads; quad += nwaves) {
        const float4 g = *reinterpret_cast<const float4*>(gnn + (size_t)quad * 256 + lane * 4);
        float a0 = g.x * wreg[0][0] + g.y * wreg[1][0] + g.z * wreg[2][0] + g.w * wreg[3][0];
        float a1 = g.x * wreg[0][1] + g.y * wreg[1][1] + g.z * wreg[2][1] + g.w * wreg[3][1];
        float a2 = g.x * wreg[0][2] + g.y * wreg[1][2] + g.z * wreg[2][2] + g.w * wreg[3][2];
#pragma unroll
        for (int off = 8; off > 0; off >>= 1) {
            a0 += __shfl_down(a0, off);
            a1 += __shfl_down(a1, off);
            a2 += __shfl_down(a2, off);
        }
        if (sub == 0) {
            const int row = quad * 4 + (lane >> 4);   // row = node*T + t
            const float s = scaler[row];
            xw[row * 3 + 0] = (a0 + b0) * s;
            xw[row * 3 + 1] = (a1 + b1) * s;
            xw[row * 3 + 2] = (a2 + b2) * s;
        }
    }
}

// ---------------------------------------------------------------------------
// Gather-sum core with maximal MLP: all 32 keys preloaded (8x int4), then all
// 32 gathers issued before any use -> one exposed memory latency per wave
// instead of four (R8 used unroll-8 batches). 4 parallel accumulators.
// ---------------------------------------------------------------------------
__device__ __forceinline__ float gather_sum(
    const float* __restrict__ cur, const int* __restrict__ keybom,
    int node, int tq)
{
    const int4* kb4 = reinterpret_cast<const int4*>(keybom + (size_t)node * KK);
    int keys[KK];
#pragma unroll
    for (int kk = 0; kk < KK / 4; ++kk) {
        const int4 k4 = kb4[kk];
        keys[kk * 4 + 0] = k4.x;
        keys[kk * 4 + 1] = k4.y;
        keys[kk * 4 + 2] = k4.z;
        keys[kk * 4 + 3] = k4.w;
    }
    float v[KK];
#pragma unroll
    for (int k = 0; k < KK; ++k) {
        const int key = keys[k];
        v[k] = (key >= 0) ? cur[(size_t)key * TQ + tq] : 0.0f;  // 32 loads in flight
    }
    float s0 = 0.f, s1 = 0.f, s2 = 0.f, s3 = 0.f;
#pragma unroll
    for (int k = 0; k < KK; k += 4) {
        s0 += v[k + 0];
        s1 += v[k + 1];
        s2 += v[k + 2];
        s3 += v[k + 3];
    }
    return (s0 + s1) + (s2 + s3);
}

// ---------------------------------------------------------------------------
// One level in XW-space, ping-pong.
// ---------------------------------------------------------------------------
__global__ __launch_bounds__(256) void level_kernel(
    const float* __restrict__ cur, const int* __restrict__ keybom,
    const int* __restrict__ lvl, float* __restrict__ nxt, int level)
{
    const int idx  = blockIdx.x * blockDim.x + threadIdx.x;
    if (idx >= NN * TQ) return;
    const int node = idx / TQ;
    const int tq   = idx - node * TQ;

    if (lvl[node] != level) {
        nxt[idx] = cur[idx];
        return;
    }
    nxt[idx] = gather_sum(cur, keybom, node, tq);
}

// ---------------------------------------------------------------------------
// Final level fused with XW -> out conversion (divide by scaler once).
// ---------------------------------------------------------------------------
__global__ __launch_bounds__(256) void level_final_kernel(
    const float* __restrict__ cur, const float* __restrict__ scaler,
    const int* __restrict__ keybom, const int* __restrict__ lvl,
    float* __restrict__ out, int level)
{
    const int idx  = blockIdx.x * blockDim.x + threadIdx.x;
    if (idx >= NN * TQ) return;
    const int node = idx / TQ;

    float v;
    if (lvl[node] != level) {
        v = cur[idx];
    } else {
        const int tq = idx - node * TQ;
        v = gather_sum(cur, keybom, node, tq);
    }
    out[idx] = v / scaler[idx / 3];      // idx/3 == node*T + t
}

extern "C" void kernel_launch(void* const* d_in, const int* in_sizes, int n_in,
                              void* d_out, int out_size, void* d_ws, size_t ws_size,
                              hipStream_t stream)
{
    const float* gnn    = (const float*)d_in[0];
    const float* w      = (const float*)d_in[1];
    const float* b      = (const float*)d_in[2];
    const float* scaler = (const float*)d_in[3];
    const int*   keybom = (const int*)d_in[4];
    const int*   lvl    = (const int*)d_in[5];
    float* out = (float*)d_out;

    char* ws = (char*)d_ws;
    float* bufA = (float*)ws;                                // NN*TQ floats (7.2 MB)
    float* bufB = (float*)(ws + (size_t)NN * TQ * 4);        // NN*TQ floats (7.2 MB)

    proj_xw_kernel<<<2048, 256, 0, stream>>>(gnn, w, b, scaler, bufA, NN * TT);

    const int blocks = (NN * TQ + 255) / 256;
    level_kernel<<<blocks, 256, 0, stream>>>(bufA, keybom, lvl, bufB, 1);
    level_kernel<<<blocks, 256, 0, stream>>>(bufB, keybom, lvl, bufA, 2);
    level_final_kernel<<<blocks, 256, 0, stream>>>(bufA, scaler, keybom, lvl, out, 3);
}